// Round 14
// baseline (55.813 us; speedup 1.0000x reference)
//
#include <hip/hip_runtime.h>

#define HH 4096
#define WW 4096
#define MAXK (1 << 20)      // == NRS * 16
#define NSP 16              // 256-px spans per row
#define SPW 256             // span width
#define NRS (HH * NSP)      // 65536 row-spans (1 per wave)
#define NBLK (NRS / 4)      // 16384 blocks, 4 waves each
#define GSPAN 1024          // spans per group
#define NGRP (NRS / GSPAN)  // 64 groups

typedef int   v4i __attribute__((ext_vector_type(4)));
typedef float v4f __attribute__((ext_vector_type(4)));

// ---------------------------------------------------------------------------
// Kernel 1: 3x3 NMS. One WAVE per 256-px row-span; lane owns 4 contiguous px.
// 5 streams/wave, shuffle halo, no LDS/barriers/atomics. PLAIN loads (NT load
// destroyed replay L3 residency — r8/r9 A/B), NT stores on mx (write-once).
// Clamp-to-edge == -inf SAME padding. XCD swizzle: 2048 blocks/XCD.
// 65536 waves: max independent dep-chains per SIMD (r8 structure, fastest
// cold-profiled k_maxima at 48 us).
// ---------------------------------------------------------------------------
__global__ __launch_bounds__(256, 8) void k_maxima(
    const float* __restrict__ rel, const float* __restrict__ rep,
    int* __restrict__ mx, unsigned char* __restrict__ masks,
    int* __restrict__ counts)
{
    const int tid  = threadIdx.x;
    const int lane = tid & 63;
    const int swz  = (blockIdx.x & 7) * (NBLK / 8) + (blockIdx.x >> 3);
    const int rs   = swz * 4 + (tid >> 6);     // row-span id, 0..NRS-1
    const int y    = rs >> 4;
    const int span = rs & (NSP - 1);
    const int x0   = span * SPW + lane * 4;

    const int xl = span ? span * SPW - 1 : 0;                    // left halo col
    const int xr = (span < NSP - 1) ? (span + 1) * SPW : WW - 1; // right halo col
    const int hx = (lane == 63) ? xr : xl;     // 2 cache lines, broadcast

    const float* rowC = rep + (size_t)y * WW;
    const float* rowU = rep + (size_t)(y > 0      ? y - 1 : 0     ) * WW;
    const float* rowD = rep + (size_t)(y < HH - 1 ? y + 1 : HH - 1) * WW;

    const v4f U = *reinterpret_cast<const v4f*>(rowU + x0);
    const v4f C = *reinterpret_cast<const v4f*>(rowC + x0);
    const v4f D = *reinterpret_cast<const v4f*>(rowD + x0);
    const v4f V = *reinterpret_cast<const v4f*>(rel + (size_t)y * WW + x0);
    const float hu = rowU[hx], hc = rowC[hx], hd = rowD[hx];

    // vertical 3-max
    const float vm0 = fmaxf(fmaxf(U.x, C.x), D.x);
    const float vm1 = fmaxf(fmaxf(U.y, C.y), D.y);
    const float vm2 = fmaxf(fmaxf(U.z, C.z), D.z);
    const float vm3 = fmaxf(fmaxf(U.w, C.w), D.w);
    const float hvm = fmaxf(fmaxf(hu, hc), hd);

    // horizontal halo via wave shuffles
    float left  = __shfl_up(vm3, 1, 64);
    float right = __shfl_down(vm0, 1, 64);
    if (lane == 0)  left  = hvm;
    if (lane == 63) right = hvm;

    const float m30 = fmaxf(fmaxf(left, vm0), vm1);
    const float m31 = fmaxf(fmaxf(vm0, vm1), vm2);
    const float m32 = fmaxf(fmaxf(vm1, vm2), vm3);
    const float m33 = fmaxf(fmaxf(vm2, vm3), right);

    unsigned int mask = 0;
    if (C.x == m30 && C.x >= 0.7f && V.x >= 0.7f) mask |= 1u;
    if (C.y == m31 && C.y >= 0.7f && V.y >= 0.7f) mask |= 2u;
    if (C.z == m32 && C.z >= 0.7f && V.z >= 0.7f) mask |= 4u;
    if (C.w == m33 && C.w >= 0.7f && V.w >= 0.7f) mask |= 8u;

    // maxima as int32 0/1, lane-contiguous, nontemporal (write-once)
    v4i o;
    o.x = mask & 1u;        o.y = (mask >> 1) & 1u;
    o.z = (mask >> 2) & 1u; o.w = (mask >> 3) & 1u;
    __builtin_nontemporal_store(o,
        reinterpret_cast<v4i*>(mx + (size_t)y * WW + x0));

    if (masks) masks[(size_t)rs * 64 + lane] = (unsigned char)mask;

    int cnt = __popc(mask);
#pragma unroll
    for (int off = 32; off; off >>= 1) cnt += __shfl_down(cnt, off, 64);
    if (lane == 0) counts[rs] = cnt;
}

// ---------------------------------------------------------------------------
// Kernel 2: per-group sums, NO atomics, fully parallel. 64 blocks x 64
// threads; block g sums counts[g*1024 .. g*1024+1024) -> gsum[g].
// ---------------------------------------------------------------------------
__global__ __launch_bounds__(64) void k_gsum(const int* __restrict__ counts,
                                             int* __restrict__ gsum)
{
    const int g    = blockIdx.x;
    const int lane = threadIdx.x;
    const int4* cp = reinterpret_cast<const int4*>(counts + g * GSPAN + lane * 16);
    const int4 a = cp[0], b = cp[1], c = cp[2], d = cp[3];
    int s = a.x + a.y + a.z + a.w + b.x + b.y + b.z + b.w
          + c.x + c.y + c.z + c.w + d.x + d.y + d.z + d.w;
#pragma unroll
    for (int off = 32; off; off >>= 1) s += __shfl_xor(s, off, 64);
    if (lane == 0) gsum[g] = s;
}

// ---------------------------------------------------------------------------
// Offset recomputation (per wave, for span rs):
//   base  = scan(gsum)[group] + sum(counts[group_base .. rs))
//   total = sum(gsum)
// All reads L2-hot (256 B gsum + 4 KB counts slice).
// ---------------------------------------------------------------------------
__device__ __forceinline__ void span_offset(
    const int* __restrict__ counts, const int* __restrict__ gsum,
    int rs, int lane, int& base, int& total)
{
    const int gv = gsum[lane];          // 64 lanes <-> 64 groups
    int ginc = gv;
#pragma unroll
    for (int off = 1; off < 64; off <<= 1) {
        int n = __shfl_up(ginc, off, 64);
        if (lane >= off) ginc += n;
    }
    total = __shfl(ginc, 63, 64);
    const int g     = rs >> 10;
    const int gbase = __shfl(ginc - gv, g, 64);

    const int rl    = rs & (GSPAN - 1);
    const int cbase = rs & ~(GSPAN - 1);
    const int4* cp  = reinterpret_cast<const int4*>(counts + cbase + lane * 16);
    const int idx = lane * 16;
    int s = 0;
#pragma unroll
    for (int j = 0; j < 4; ++j) {
        const int4 c = cp[j];
        s += (idx + 4 * j + 0 < rl) ? c.x : 0;
        s += (idx + 4 * j + 1 < rl) ? c.y : 0;
        s += (idx + 4 * j + 2 < rl) ? c.z : 0;
        s += (idx + 4 * j + 3 < rl) ? c.w : 0;
    }
#pragma unroll
    for (int off = 32; off; off >>= 1) s += __shfl_xor(s, off, 64);
    base = gbase + s;
}

// ---------------------------------------------------------------------------
// Kernel 3a: ordered compaction, one WAVE per 256-px row-span, offsets
// recomputed locally. Fused -1 tail fill: span rs owns slots [rs*16,rs*16+16).
// ---------------------------------------------------------------------------
__global__ __launch_bounds__(256) void k_emit_ws(
    const unsigned char* __restrict__ masks, const int* __restrict__ counts,
    const int* __restrict__ gsum, int* __restrict__ oy, int* __restrict__ ox)
{
    const int tid  = threadIdx.x;
    const int lane = tid & 63;
    const int rs   = blockIdx.x * 4 + (tid >> 6);

    int base, total;
    span_offset(counts, gsum, rs, lane, base, total);

    if (lane < 16) {
        const int slot = rs * 16 + lane;
        if (slot >= total) { oy[slot] = -1; ox[slot] = -1; }
    }

    unsigned int mask = masks[(size_t)rs * 64 + lane];

    const int cnt = __popc(mask);
    int inc = cnt;
#pragma unroll
    for (int off = 1; off < 64; off <<= 1) {
        int n = __shfl_up(inc, off, 64);
        if (lane >= off) inc += n;
    }

    int pos = base + inc - cnt;
    const int y  = rs >> 4;
    const int xb = (rs & (NSP - 1)) * SPW + lane * 4;
    while (mask) {
        int b = __ffs(mask) - 1;
        mask &= mask - 1;
        if (pos < MAXK) { oy[pos] = y; ox[pos] = xb + b; }
        ++pos;
    }
}

// ---------------------------------------------------------------------------
// Kernel 3b: fallback — rebuild masks from the int32 maxima array.
// ---------------------------------------------------------------------------
__global__ __launch_bounds__(256) void k_emit_mx(
    const int* __restrict__ mx, const int* __restrict__ counts,
    const int* __restrict__ gsum, int* __restrict__ oy, int* __restrict__ ox)
{
    const int tid  = threadIdx.x;
    const int lane = tid & 63;
    const int rs   = blockIdx.x * 4 + (tid >> 6);
    const int y    = rs >> 4;
    const int xb   = (rs & (NSP - 1)) * SPW + lane * 4;

    int base, total;
    span_offset(counts, gsum, rs, lane, base, total);

    if (lane < 16) {
        const int slot = rs * 16 + lane;
        if (slot >= total) { oy[slot] = -1; ox[slot] = -1; }
    }

    const int4 f = *reinterpret_cast<const int4*>(mx + (size_t)y * WW + xb);
    unsigned int mask = 0;
    if (f.x) mask |= 1u;
    if (f.y) mask |= 2u;
    if (f.z) mask |= 4u;
    if (f.w) mask |= 8u;

    const int cnt = __popc(mask);
    int inc = cnt;
#pragma unroll
    for (int off = 1; off < 64; off <<= 1) {
        int n = __shfl_up(inc, off, 64);
        if (lane >= off) inc += n;
    }

    int pos = base + inc - cnt;
    while (mask) {
        int b = __ffs(mask) - 1;
        mask &= mask - 1;
        if (pos < MAXK) { oy[pos] = y; ox[pos] = xb + b; }
        ++pos;
    }
}

// ---------------------------------------------------------------------------
extern "C" void kernel_launch(void* const* d_in, const int* in_sizes, int n_in,
                              void* d_out, int out_size, void* d_ws, size_t ws_size,
                              hipStream_t stream)
{
    const float* rel = (const float*)d_in[0];   // reliability
    const float* rep = (const float*)d_in[1];   // repeatability

    int* out = (int*)d_out;
    int* mx  = out;                       // 4096*4096 maxima (int32 0/1)
    int* oy  = out + (size_t)HH * WW;     // 2^20 y coords
    int* ox  = oy + MAXK;                 // 2^20 x coords

    int* counts = (int*)d_ws;                         // NRS ints
    int* gsum   = counts + NRS;                       // NGRP ints (+pad)
    unsigned char* masks = (unsigned char*)(gsum + NGRP + 16);  // NRS*64 B

    const size_t need_ws = (size_t)(NRS + NGRP + 16) * sizeof(int)
                         + (size_t)NRS * 64;
    const bool use_masks = ws_size >= need_ws;

    k_maxima<<<NBLK, 256, 0, stream>>>(rel, rep, mx,
                                       use_masks ? masks : nullptr, counts);
    k_gsum<<<NGRP, 64, 0, stream>>>(counts, gsum);
    if (use_masks)
        k_emit_ws<<<NRS / 4, 256, 0, stream>>>(masks, counts, gsum, oy, ox);
    else
        k_emit_mx<<<NRS / 4, 256, 0, stream>>>(mx, counts, gsum, oy, ox);
}